// Round 8
// baseline (224.264 us; speedup 1.0000x reference)
//
#include <hip/hip_runtime.h>

// SpikingCell recurrence, dead-code-eliminated (absmax=0 verified R0-R6):
//   dvi = (refrac >= 2) ? buf : 0
//   v += dvi; o = (v >= 1); v -= o
//   refrac = o ? 0 : refrac + 1
//   buf = x[b,t,n]
//
// R7 post-mortem: compile error only — __builtin_nontemporal_* rejects
// HIP_vector_type<float,4>; use a clang native ext_vector_type(4) instead.
// Experiment unchanged: NT hints (R6's win: L2 write-allocate interference
// was the 82-87us plateau) + 1 KB dwordx4 wave-bursts (R4 skeleton). Under
// NT the requests hit fabric/HBM directly, so transaction size should now
// matter. 128-thread blocks, 256 blocks (1/CU), U=8 float4 ping-pong.

typedef float vfloat4 __attribute__((ext_vector_type(4)));

constexpr int B = 16;
constexpr int T = 256;
constexpr int N = 8192;
constexpr int U = 8;       // pipeline depth in t-steps
constexpr int C4 = N / 4;  // float4 columns per batch row = 2048

__global__ __launch_bounds__(128) void spiking_kernel(
    const vfloat4* __restrict__ x, vfloat4* __restrict__ out) {
  const int gid = blockIdx.x * 128 + threadIdx.x;  // 0 .. B*C4-1
  const int b = gid / C4;
  const int n4 = gid - b * C4;

  const vfloat4* __restrict__ xp = x + (size_t)b * T * C4 + n4;
  vfloat4* __restrict__ op = out + (size_t)b * T * C4 + n4;

  float v[4] = {0.f, 0.f, 0.f, 0.f};
  float refrac[4] = {0.f, 0.f, 0.f, 0.f};
  float buf[4] = {0.f, 0.f, 0.f, 0.f};

  vfloat4 cur[U], nxt[U];

#pragma unroll
  for (int u = 0; u < U; ++u)
    cur[u] = __builtin_nontemporal_load(xp + (size_t)u * C4);

#pragma unroll 1
  for (int g = 0; g < T / U - 1; ++g) {
    const size_t base_next = (size_t)(g + 1) * U * C4;
#pragma unroll
    for (int u = 0; u < U; ++u)
      nxt[u] = __builtin_nontemporal_load(xp + base_next + (size_t)u * C4);

    const size_t base_cur = (size_t)g * U * C4;
#pragma unroll
    for (int u = 0; u < U; ++u) {
      vfloat4 o;
#pragma unroll
      for (int j = 0; j < 4; ++j) {
        const float xj = cur[u][j];
        const float dvi = (refrac[j] >= 2.0f) ? buf[j] : 0.0f;
        v[j] += dvi;
        const float oj = (v[j] >= 1.0f) ? 1.0f : 0.0f;
        v[j] -= oj;
        refrac[j] = (oj == 0.0f) ? (refrac[j] + 1.0f) : 0.0f;
        buf[j] = xj;
        o[j] = oj;
      }
      __builtin_nontemporal_store(o, op + base_cur + (size_t)u * C4);
    }

#pragma unroll
    for (int u = 0; u < U; ++u) cur[u] = nxt[u];
  }

  // Epilogue: last U timesteps.
  const size_t base_last = (size_t)(T - U) * C4;
#pragma unroll
  for (int u = 0; u < U; ++u) {
    vfloat4 o;
#pragma unroll
    for (int j = 0; j < 4; ++j) {
      const float xj = cur[u][j];
      const float dvi = (refrac[j] >= 2.0f) ? buf[j] : 0.0f;
      v[j] += dvi;
      const float oj = (v[j] >= 1.0f) ? 1.0f : 0.0f;
      v[j] -= oj;
      refrac[j] = (oj == 0.0f) ? (refrac[j] + 1.0f) : 0.0f;
      buf[j] = xj;
      o[j] = oj;
    }
    __builtin_nontemporal_store(o, op + base_last + (size_t)u * C4);
  }
}

extern "C" void kernel_launch(void* const* d_in, const int* in_sizes, int n_in,
                              void* d_out, int out_size, void* d_ws,
                              size_t ws_size, hipStream_t stream) {
  const vfloat4* x = (const vfloat4*)d_in[0];
  vfloat4* out = (vfloat4*)d_out;

  const int threads = 128;
  const int total = B * C4;            // one thread per float4 column
  const int blocks = total / threads;  // 256 blocks -> 1 block/CU, 2 waves/CU
  spiking_kernel<<<blocks, threads, 0, stream>>>(x, out);
}